// Round 1
// baseline (103.848 us; speedup 1.0000x reference)
//
#include <hip/hip_runtime.h>
#include <stdint.h>

// Problem constants (from reference setup_inputs)
#define BB    8
#define NN    16384
#define KK    1024
#define KNN   16
#define CPB   8            // centers per block (R12: was 4 -> amortize xs/loads 2x)
#define WPB   8            // waves per block (512 threads); wave q owns eighth q
#define EGRP  (NN / 4 / WPB)  // float4-groups (4 pts) per eighth = 512
#define PGRP  128          // pilot groups per eighth (=512 pts; sample/center = 4096, same as R11)
#define TCAP  256          // survivor cap per center (total; = depth-4 exactness bound)

typedef unsigned long long u64;

// Manual 64-bit shuffle-xor (two 32-bit shuffles).
__device__ __forceinline__ u64 shfl_xor_u64(u64 v, int mask) {
    int lo = (int)(uint32_t)v;
    int hi = (int)(uint32_t)(v >> 32);
    lo = __shfl_xor(lo, mask, 64);
    hi = __shfl_xor(hi, mask, 64);
    return ((u64)(uint32_t)hi << 32) | (u64)(uint32_t)lo;
}

// 64-bit shuffle from a dynamic source lane.
__device__ __forceinline__ u64 shfl_u64(u64 v, int src) {
    int lo = __shfl((int)(uint32_t)v, src, 64);
    int hi = __shfl((int)(uint32_t)(v >> 32), src, 64);
    return ((u64)(uint32_t)hi << 32) | (u64)(uint32_t)lo;
}

// Butterfly min over all 64 lanes; every lane ends with the wave minimum.
__device__ __forceinline__ u64 wave_min_u64(u64 v) {
#pragma unroll
    for (int off = 32; off > 0; off >>= 1) {
        u64 o = shfl_xor_u64(v, off);
        v = o < v ? o : v;
    }
    return v;
}

// Full 64-lane bitonic sort (ascending) of u64 keys carrying a 32-bit payload.
// Keys assumed unique except padding (~0ull); payload corruption on equal-key
// exchange only affects padding entries, which never reach positions 0..15
// (>=16 real keys guaranteed by the pilot-threshold argument).
__device__ __forceinline__ void sort64_kv(u64& key, uint32_t& pay, int lane) {
#pragma unroll
    for (int k = 2; k <= 64; k <<= 1) {
#pragma unroll
        for (int j = k >> 1; j > 0; j >>= 1) {
            u64 okey = shfl_xor_u64(key, j);
            uint32_t opay = (uint32_t)__shfl_xor((int)pay, j, 64);
            bool tmin = ((lane & j) == 0) == ((lane & k) == 0);
            bool osm = okey < key;
            bool take = tmin ? osm : !osm;
            if (take) { key = okey; pay = opay; }
        }
    }
}

// Full 64-lane bitonic sort (ascending) of u64 keys, no payload.
__device__ __forceinline__ void sort64_k(u64& key, int lane) {
#pragma unroll
    for (int k = 2; k <= 64; k <<= 1) {
#pragma unroll
        for (int j = k >> 1; j > 0; j >>= 1) {
            u64 okey = shfl_xor_u64(key, j);
            bool tmin = ((lane & j) == 0) == ((lane & k) == 0);
            bool osm = okey < key;
            bool take = tmin ? osm : !osm;
            if (take) key = okey;
        }
    }
}

// EXACT reference d2 (final ranking + fallback): cross = sequential FMA chain
// (einsum -> dot_general -> BLAS microkernel semantics, verified R3);
// x_sq/c_sq plain non-FMA reduce, elementwise ops left-to-right.
__device__ __forceinline__ float point_d2(const float* xb, int i,
                                          float c0, float c1, float c2, float csq) {
#pragma clang fp contract(off)
    float x0 = xb[i * 3 + 0];
    float x1 = xb[i * 3 + 1];
    float x2 = xb[i * 3 + 2];
    float xsq = (x0 * x0 + x1 * x1) + x2 * x2;
    float cross = __fmaf_rn(x2, c2, __fmaf_rn(x1, c1, x0 * c0));
    float d2 = (xsq + csq) - 2.0f * cross;
    return d2 < 0.0f ? 0.0f : d2;   // jnp.maximum(d2, 0)
}

// Cold-path exact fallback (full-N bubble scan), only on cap overflow.
__device__ __attribute__((noinline)) int fallback_scan(const float* xb,
                                                       float c0, float c1, float c2,
                                                       float csq, int lane) {
    u64 list[KNN];
#pragma unroll
    for (int j = 0; j < KNN; ++j) list[j] = ~0ull;
    for (int i = lane; i < NN; i += 64) {
        float d2 = point_d2(xb, i, c0, c1, c2, csq);
        float dist = __fsqrt_rn(d2);
        u64 key = ((u64)__float_as_uint(dist) << 32) | (u64)(uint32_t)i;
        if (key < list[KNN - 1]) {
#pragma unroll
            for (int j = 0; j < KNN; ++j) {
                bool lt = key < list[j];
                u64 lo = lt ? key : list[j];
                u64 hi = lt ? list[j] : key;
                list[j] = lo;
                key = hi;
            }
        }
    }
    int res = 0;
    for (int it = 0; it < KNN; ++it) {
        u64 best = wave_min_u64(list[0]);
        if (it == lane) res = (int)(uint32_t)best;
        if (list[0] == best) {
#pragma unroll
            for (int j = 0; j < KNN - 1; ++j) list[j] = list[j + 1];
            list[KNN - 1] = ~0ull;
        }
    }
    return res;
}

// 16th-smallest FLOAT (true float order incl. negatives) of the 64 lane
// values, via full bitonic sort across lanes; lane 15 holds the answer.
__device__ __forceinline__ float sixteenth_smallest(float m, int lane) {
    uint32_t u = __float_as_uint(m);
    uint32_t s = (u & 0x80000000u) ? ~u : (u | 0x80000000u);  // sortable bits
    u64 v = ((u64)s << 32) | (unsigned)lane;                  // unique keys
#pragma unroll
    for (int k = 2; k <= 64; k <<= 1) {
#pragma unroll
        for (int j = k >> 1; j > 0; j >>= 1) {
            u64 o = shfl_xor_u64(v, j);
            bool up = (lane & k) == 0;          // k=64: ascending
            bool takeMin = ((lane & j) == 0) == up;
            u64 mn = v < o ? v : o;
            u64 mx = v < o ? o : v;
            v = takeMin ? mn : mx;
        }
    }
    uint32_t sb = (uint32_t)__shfl((int)(uint32_t)(v >> 32), 15, 64);
    uint32_t ub = (sb & 0x80000000u) ? (sb ^ 0x80000000u) : ~sb;
    return __uint_as_float(ub);
}

// Unpack a group of 4 points (3 float4 = 48 B) + their exact xs.
__device__ __forceinline__ void load_group(const float4* x4, int g,
                                           float (&px)[4], float (&py)[4],
                                           float (&pz)[4], float (&xs)[4]) {
#pragma clang fp contract(off)
    float4 f0 = x4[g * 3 + 0];
    float4 f1 = x4[g * 3 + 1];
    float4 f2 = x4[g * 3 + 2];
    px[0] = f0.x; py[0] = f0.y; pz[0] = f0.z;
    px[1] = f0.w; py[1] = f1.x; pz[1] = f1.y;
    px[2] = f1.z; py[2] = f1.w; pz[2] = f2.x;
    px[3] = f2.y; py[3] = f2.z; pz[3] = f2.w;
#pragma unroll
    for (int k = 0; k < 4; ++k)
        xs[k] = (px[k] * px[k] + py[k] * py[k]) + pz[k] * pz[k];  // non-FMA, exact
}

// R12 structure: block = 8 waves (512 thr) owns EIGHT consecutive centers; wave
// q scans eighth q (2048 pts) for all 8 centers -> load/xs/address overhead per
// pair halves vs the 4-center version. Survivors go to ONE shared list per
// center (single LDS atomic counter; storage order irrelevant since rerank
// sorts exact u64 keys).
//   Phase 1 (pilot): per-lane min of d' = xs - 2*x.c over first PGRP groups of
//     the eighth; min across 8 waves via LDS, one bitonic -> T (same 4096-pt
//     sample per center as R11 -> identical T statistics).
//   Phase 2 (filter): d' <= U = T + |T|*1e-5 + 5e-4 (verified R5-R10).
//   Phase 3: wave q reranks center q (total <= 256 -> <= 4 keys/lane exact).
//     Selection = two bitonic sorts (sort l0s w/ lane payload; top-16 keys can
//     only live in the 16 lanes owning the 16 smallest l0s; gather their
//     4-lists, sort 64) instead of 16 serial wave-mins (96 -> 46 chain steps).
__global__ __launch_bounds__(512, 4) void knn_kernel(const float* __restrict__ xyz,
                                                     const float* __restrict__ centers,
                                                     int* __restrict__ out) {
#pragma clang fp contract(off)
    const int q = (int)(threadIdx.x >> 6);    // wave in block = eighth = owned center
    const int lane = (int)(threadIdx.x & 63);
    const int cbase = (int)blockIdx.x * CPB;  // global center id of center 0
    const int b = cbase >> 10;                // batch (1024 % 8 == 0: no straddle)

    __shared__ float    s_min[CPB][512];      // [center][tid] 16 KB
    __shared__ float    s_T[CPB];
    __shared__ int      s_cnt[CPB];
    __shared__ uint32_t s_idx[CPB][TCAP];     // 8 KB

    // folded center consts: n = -2*c (exact)
    float n[CPB][3];
#pragma unroll
    for (int c = 0; c < CPB; ++c) {
        n[c][0] = -2.0f * centers[(cbase + c) * 3 + 0];
        n[c][1] = -2.0f * centers[(cbase + c) * 3 + 1];
        n[c][2] = -2.0f * centers[(cbase + c) * 3 + 2];
    }

    const float* xb = xyz + (size_t)b * NN * 3;
    const float4* x4 = (const float4*)xb;     // batch base is 16B-aligned
    const int gbase = q * EGRP;               // first group of this eighth

    // ---- Phase 1: pilot minima over first PGRP groups of this eighth ----
    float m[CPB];
#pragma unroll
    for (int c = 0; c < CPB; ++c) m[c] = __builtin_inff();
#pragma unroll
    for (int s = 0; s < PGRP / 64; ++s) {     // 2 superiters
        int g = gbase + s * 64 + lane;
        float px[4], py[4], pz[4], xs[4];
        load_group(x4, g, px, py, pz, xs);
#pragma unroll
        for (int k = 0; k < 4; ++k) {
#pragma unroll
            for (int c = 0; c < CPB; ++c) {
                float d = __fmaf_rn(px[k], n[c][0],
                          __fmaf_rn(py[k], n[c][1],
                          __fmaf_rn(pz[k], n[c][2], xs[k])));
                m[c] = d < m[c] ? d : m[c];
            }
        }
    }
#pragma unroll
    for (int c = 0; c < CPB; ++c) s_min[c][threadIdx.x] = m[c];
    if (threadIdx.x < CPB) s_cnt[threadIdx.x] = 0;
    __syncthreads();
    {
        // wave q: per-lane min across the 8 source waves for center q, then
        // one bitonic. Each min-of-8 is still a single real point's d'.
        float v = s_min[q][lane];
#pragma unroll
        for (int w = 1; w < WPB; ++w) v = fminf(v, s_min[q][w * 64 + lane]);
        float t = sixteenth_smallest(v, lane);
        if (lane == 0) s_T[q] = t;
    }
    __syncthreads();
    float U[CPB];
#pragma unroll
    for (int c = 0; c < CPB; ++c) {
        float T = s_T[c];
        U[c] = T + fabsf(T) * 1e-5f + 5e-4f;  // verified slack (R5-R10)
    }

    // ---- Phase 2: filter scan; divergent atomic compaction into LDS ----
#pragma unroll 2
    for (int s = 0; s < EGRP / 64; ++s) {     // 8 superiters
        int g = gbase + s * 64 + lane;
        float px[4], py[4], pz[4], xs[4];
        load_group(x4, g, px, py, pz, xs);
#pragma unroll
        for (int k = 0; k < 4; ++k) {
            int i = g * 4 + k;                // batch-local point index
#pragma unroll
            for (int c = 0; c < CPB; ++c) {
                float d = __fmaf_rn(px[k], n[c][0],
                          __fmaf_rn(py[k], n[c][1],
                          __fmaf_rn(pz[k], n[c][2], xs[k])));
                if (d <= U[c]) {
                    int pos = atomicAdd(&s_cnt[c], 1);
                    if (pos < TCAP) s_idx[c][pos] = (uint32_t)i;
                }
            }
        }
    }
    __syncthreads();

    // ---- Phase 3: wave q reranks center q exactly (no idle waves) ----
    const int cc = cbase + q;
    const float c0 = centers[cc * 3 + 0];
    const float c1 = centers[cc * 3 + 1];
    const float c2 = centers[cc * 3 + 2];
    const float csq = (c0 * c0 + c1 * c1) + c2 * c2;  // exact non-FMA reduce
    const int total = s_cnt[q];

    uint32_t outIdx;
    if (total <= TCAP) {
        // <= 4 keys/lane round-robin -> depth-4 list holds ALL of a lane's
        // keys -> union is the full survivor set (exact).
        u64 l0 = ~0ull, l1 = ~0ull, l2 = ~0ull, l3 = ~0ull;
        for (int j = lane; j < total; j += 64) {
            int idx = (int)s_idx[q][j];
            float d2 = point_d2(xb, idx, c0, c1, c2, csq);
            u64 key = ((u64)__float_as_uint(__fsqrt_rn(d2)) << 32) | (u64)(uint32_t)idx;
            bool t;
            t = key < l0; { u64 lo = t ? key : l0, hi = t ? l0 : key; l0 = lo; key = hi; }
            t = key < l1; { u64 lo = t ? key : l1, hi = t ? l1 : key; l1 = lo; key = hi; }
            t = key < l2; { u64 lo = t ? key : l2, hi = t ? l2 : key; l2 = lo; key = hi; }
            t = key < l3; { u64 lo = t ? key : l3, hi = t ? l3 : key; l3 = lo; key = hi; }
        }
        // Selection: sort1 over per-lane minima (l0) with source-lane payload.
        // >=16 real keys exist (16 pilot points with d' <= T <= U), so
        // positions 0..15 are real, unique, correctly ordered.
        u64 key = l0;
        uint32_t pay = (uint32_t)lane;
        sort64_kv(key, pay, lane);
        // Gather: lane i takes element (i&3) of the lane ranked (i>>2).
        int pos = lane >> 2, elem = lane & 3;
        int sid = __shfl((int)pay, pos, 64);
        u64 g0 = shfl_u64(l0, sid);
        u64 g1 = shfl_u64(l1, sid);
        u64 g2 = shfl_u64(l2, sid);
        u64 g3 = shfl_u64(l3, sid);
        u64 gk = (elem == 0) ? g0 : (elem == 1) ? g1 : (elem == 2) ? g2 : g3;
        // sort2: 64 candidate keys (superset of global top-16) -> lanes 0..15
        // hold ranks 0..15 in exact (dist,idx) order.
        sort64_k(gk, lane);
        outIdx = (uint32_t)gk;
    } else {
        outIdx = (uint32_t)fallback_scan(xb, c0, c1, c2, csq, lane);
    }

    // out[b][rank][c_in_batch]
    if (lane < KNN) {
        out[((size_t)b * KNN + lane) * KK + (cc & 1023)] = (int)outIdx;
    }
}

extern "C" void kernel_launch(void* const* d_in, const int* in_sizes, int n_in,
                              void* d_out, int out_size, void* d_ws, size_t ws_size,
                              hipStream_t stream) {
    const float* xyz = (const float*)d_in[0];
    const float* centers = (const float*)d_in[1];
    int* out = (int*)d_out;
    (void)d_ws; (void)ws_size;

    const int nblocks = BB * KK / CPB;   // 1024 blocks x 8 waves
    hipLaunchKernelGGL(knn_kernel, dim3(nblocks), dim3(512), 0, stream,
                       xyz, centers, out);
}